// Round 12
// baseline (977.584 us; speedup 1.0000x reference)
//
#include <hip/hip_runtime.h>
#include <math.h>

// Problem constants
#define Bq 2
#define Nq 4096
#define Dq 64
#define MAXR 14          // rounds launched = supports n_eps up to 12 (diameter <= ~187)
#define RBAND 16         // rows per k_iter block / band granularity
#define NBAND (Nq / RBAND)            // 256 bands
#define W_LOG (-8.317766166719343f)   // -log(4096) (N == M, uniform weights)
#define WL2   (-12.0f)                // W_LOG * LOG2E = -log2(4096), EXACT
#define LOG2E 1.4426950408889634f
#define LN2   0.6931471805599453f
#define DQ_SCALE (4.0f / 65535.0f)    // u16 -> C dequant
#define Q_SCALE  16383.75f            // C -> u16 quant (65535/4, exact in f32)
#define ACLAMP 88.0f                  // exp2-arg clamp on hoisted duals (legit max ~72)
#define SFLOOR 1e-30f                 // LSE sum floor: prevents log(0)

// ---- workspace layout (float offsets) — identical to R11 ----
#define F_XN   ((size_t)0)                               // normalized x f32: B*N*D
#define F_YN   (F_XN + (size_t)Bq * Nq * Dq)             // normalized y f32
#define F_XH   (F_YN + (size_t)Bq * Nq * Dq)             // bf16 hi(x): B*N*D u16
#define F_XL   (F_XH + (size_t)Bq * Nq * Dq / 2)         // bf16 lo(x)
#define F_YH   (F_XL + (size_t)Bq * Nq * Dq / 2)
#define F_YL   (F_YH + (size_t)Bq * Nq * Dq / 2)
#define F_FG   (F_YL + (size_t)Bq * Nq * Dq / 2)         // duals: 2 copies x 4 arrays x B*N
#define F_EPS  (F_FG + (size_t)2 * 4 * Bq * Nq)          // [0..7]=ints, [8..]=eps values
#define F_MM   (F_EPS + 64)                              // minmax partials: 64 x 128
#define F_CP   (F_MM + (size_t)64 * 128)                 // op0 col partials: B*NBAND*N
#define F_C    (((F_CP + (size_t)Bq * NBAND * Nq) + 3) & ~(size_t)3)  // 3 cost mats u16
#define GSZ    ((size_t)Bq * Nq * Nq)                    // u16 elements per matrix
#define F_CPS  (F_C + 3 * GSZ / 2)                       // sym partials: 2 ops x B x NBAND x N
#define F_TOTAL_OLD (F_C + 3 * GSZ / 2)                  // ~218 MB (R10-proven)
#define F_TOTAL_SYM (F_CPS + (size_t)2 * Bq * NBAND * Nq) // ~234 MB
#define F_TOTAL_S (F_C)                                  // ~17 MB fallback footprint

typedef short short8v __attribute__((ext_vector_type(8)));   // 8 bf16 bits (4 VGPRs)
typedef float f32x4 __attribute__((ext_vector_type(4)));

__device__ __forceinline__ unsigned short f2bf(float f) {
    unsigned u = __float_as_uint(f);
    unsigned r = (u + 0x7fffu + ((u >> 16) & 1u)) >> 16;   // RNE
    return (unsigned short)r;
}
__device__ __forceinline__ float bf2f(unsigned short b) {
    return __uint_as_float(((unsigned)b) << 16);
}

// ---------------- normalize points (+ split-bf16 copies) ----------------
__global__ __launch_bounds__(256) void k_normalize(const float* __restrict__ x,
                                                   const float* __restrict__ y,
                                                   float* __restrict__ ws) {
    int gid = blockIdx.x * 256 + threadIdx.x;
    int wave = gid >> 6;                // point id across both tensors
    int lane = gid & 63;                // dim (D == 64)
    int tensor = wave / (Bq * Nq);
    int p = wave % (Bq * Nq);
    const float* src = tensor ? y : x;
    float v = src[(size_t)p * Dq + lane];
    float s = v * v;
    #pragma unroll
    for (int o = 32; o > 0; o >>= 1) s += __shfl_xor(s, o);
    float vn = v / sqrtf(s);
    float* dst = ws + (tensor ? F_YN : F_XN);
    dst[(size_t)p * Dq + lane] = vn;
    unsigned short hb = f2bf(vn);
    float lo = vn - bf2f(hb);
    unsigned short lb = f2bf(lo);
    unsigned short* dh = (unsigned short*)(ws + (tensor ? F_YH : F_XH));
    unsigned short* dl = (unsigned short*)(ws + (tensor ? F_YL : F_XL));
    dh[(size_t)p * Dq + lane] = hb;
    dl[(size_t)p * Dq + lane] = lb;
}

// ---------------- per-dim max/min partials (raw inputs, both clouds) ----------------
__global__ __launch_bounds__(256) void k_minmax(const float* __restrict__ x,
                                                const float* __restrict__ y,
                                                float* __restrict__ ws) {
    int d = threadIdx.x & 63, q = threadIdx.x >> 6;
    int p0 = blockIdx.x * 256;
    float mx = -INFINITY, mn = INFINITY;
    for (int p = p0 + q; p < p0 + 256; p += 4) {
        const float* src = (p < Bq * Nq) ? x : y;
        int pp = (p < Bq * Nq) ? p : p - Bq * Nq;
        float v = src[(size_t)pp * Dq + d];
        mx = fmaxf(mx, v); mn = fminf(mn, v);
    }
    __shared__ float smx[4][64], smn[4][64];
    smx[q][d] = mx; smn[q][d] = mn;
    __syncthreads();
    if (threadIdx.x < 64) {
        float a = fmaxf(fmaxf(smx[0][d], smx[1][d]), fmaxf(smx[2][d], smx[3][d]));
        float i = fminf(fminf(smn[0][d], smn[1][d]), fminf(smn[2][d], smn[3][d]));
        ws[F_MM + (size_t)blockIdx.x * 128 + d] = a;
        ws[F_MM + (size_t)blockIdx.x * 128 + 64 + d] = i;
    }
}

// ---------------- diameter + eps schedule (np.arange semantics, f64) ----------------
__global__ void k_eps(float* __restrict__ ws) {
    int d = threadIdx.x;  // 64 threads = 1 wave
    float mx = -INFINITY, mn = INFINITY;
    for (int k = 0; k < 64; k++) {
        mx = fmaxf(mx, ws[F_MM + (size_t)k * 128 + d]);
        mn = fminf(mn, ws[F_MM + (size_t)k * 128 + 64 + d]);
    }
    float r = mx - mn;
    float r2 = r * r;
    #pragma unroll
    for (int o = 32; o > 0; o >>= 1) r2 += __shfl_xor(r2, o);
    if (d == 0) {
        double dd = (double)sqrtf(r2);               // f32-rounded diameter like np
        double start = 2.0 * log(dd);                // P * log(diameter)
        double stop  = 2.0 * log(sqrt(0.1));         // P * log(BLUR)
        double step  = 2.0 * log(0.5);               // P * log(SCALING)
        double lend = ceil((stop - start) / step);
        int len = (lend <= 0.0) ? 0 : (int)lend;
        int n = len + 2;                             // len(eps_list)
        if (n > MAXR - 2) n = MAXR - 2;
        int* ei = (int*)(ws + F_EPS);
        ei[0] = n;
        float* ev = ws + F_EPS + 8;
        ev[0] = (float)(dd * dd);
        for (int i = 0; i < len && i + 1 < n - 1; i++)
            ev[1 + i] = (float)exp(start + i * step);
        ev[n - 1] = 0.1f;                            // BLUR**P
    }
}

// ------- cost matrices via split-bf16 MFMA, LDS-staged 64x64 tiles -> u16 -------
// op0 C_xy, op1 C_xx, op2 C_yy.  skipLower: omit strictly-lower tiles of xx/yy.
__global__ __launch_bounds__(256) void k_gram_mfma(float* __restrict__ ws, int skipLower) {
    int op = blockIdx.z, b = blockIdx.y;
    int tr = (blockIdx.x & 63) * 64;
    int tc = (blockIdx.x >> 6) * 64;
    if (skipLower && op != 0 && tc + 64 <= tr) return;   // never read by sym path
    const unsigned short* AH = (const unsigned short*)(ws + (op == 2 ? F_YH : F_XH)) + (size_t)b * Nq * Dq;
    const unsigned short* AL = (const unsigned short*)(ws + (op == 2 ? F_YL : F_XL)) + (size_t)b * Nq * Dq;
    const unsigned short* BH = (const unsigned short*)(ws + (op == 1 ? F_XH : F_YH)) + (size_t)b * Nq * Dq;
    const unsigned short* BL = (const unsigned short*)(ws + (op == 1 ? F_XL : F_YL)) + (size_t)b * Nq * Dq;

    __shared__ unsigned short sbuf[4][64][72];
    #define sAh (sbuf[0])
    #define sAl (sbuf[1])
    #define sBh (sbuf[2])
    #define sBl (sbuf[3])
    #define sC  (sbuf[0])

    #pragma unroll
    for (int i = 0; i < 2; i++) {
        int c = threadIdx.x + 256 * i;         // 512 chunks of 8 u16 per matrix
        int row = c >> 3, pos = c & 7;
        size_t sa = (size_t)(tr + row) * Dq + pos * 8;
        size_t sb = (size_t)(tc + row) * Dq + pos * 8;
        *(uint4*)&sAh[row][pos * 8] = *(const uint4*)&AH[sa];
        *(uint4*)&sAl[row][pos * 8] = *(const uint4*)&AL[sa];
        *(uint4*)&sBh[row][pos * 8] = *(const uint4*)&BH[sb];
        *(uint4*)&sBl[row][pos * 8] = *(const uint4*)&BL[sb];
    }
    __syncthreads();

    int w = threadIdx.x >> 6, lane = threadIdx.x & 63;
    int m = lane & 15, kb = lane >> 4;
    int ar = w * 16 + m;
    short8v aH0 = *(const short8v*)&sAh[ar][kb * 8];
    short8v aH1 = *(const short8v*)&sAh[ar][32 + kb * 8];
    short8v aL0 = *(const short8v*)&sAl[ar][kb * 8];
    short8v aL1 = *(const short8v*)&sAl[ar][32 + kb * 8];
    __syncthreads();   // sAh now dead -> reuse as sC

    #pragma unroll
    for (int cb = 0; cb < 4; cb++) {
        int bc = cb * 16 + m;
        short8v bH0 = *(const short8v*)&sBh[bc][kb * 8];
        short8v bH1 = *(const short8v*)&sBh[bc][32 + kb * 8];
        short8v bL0 = *(const short8v*)&sBl[bc][kb * 8];
        short8v bL1 = *(const short8v*)&sBl[bc][32 + kb * 8];
        f32x4 acc = {0.f, 0.f, 0.f, 0.f};
        acc = __builtin_amdgcn_mfma_f32_16x16x32_bf16(aH0, bH0, acc, 0, 0, 0);
        acc = __builtin_amdgcn_mfma_f32_16x16x32_bf16(aH1, bH1, acc, 0, 0, 0);
        acc = __builtin_amdgcn_mfma_f32_16x16x32_bf16(aL0, bH0, acc, 0, 0, 0);
        acc = __builtin_amdgcn_mfma_f32_16x16x32_bf16(aL1, bH1, acc, 0, 0, 0);
        acc = __builtin_amdgcn_mfma_f32_16x16x32_bf16(aH0, bL0, acc, 0, 0, 0);
        acc = __builtin_amdgcn_mfma_f32_16x16x32_bf16(aH1, bL1, acc, 0, 0, 0);
        int colblk = cb * 2 + (m >> 3);
        int within = m & 7;
        #pragma unroll
        for (int rr = 0; rr < 4; rr++) {
            int rowl = w * 16 + kb * 4 + rr;
            float c1 = 1.0f - acc[rr];
            unsigned u = __float2uint_rn(fminf(c1 * c1, 4.0f) * Q_SCALE);
            if (u > 65535u) u = 65535u;
            int swz = colblk ^ ((rowl >> 1) & 7);
            sC[rowl][swz * 8 + within] = (unsigned short)u;
        }
    }
    __syncthreads();

    unsigned short* C = (unsigned short*)(ws + F_C) + (size_t)op * GSZ + (size_t)b * Nq * Nq;
    #pragma unroll
    for (int i = 0; i < 2; i++) {
        int c = threadIdx.x + 256 * i;
        int row = c >> 3, pos = c & 7;
        int swz = pos ^ ((row >> 1) & 7);
        uint4 v = *(const uint4*)&sC[row][swz * 8];
        *(uint4*)&C[(size_t)(tr + row) * Nq + tc + pos * 8] = v;
    }
    #undef sAh
    #undef sAl
    #undef sBh
    #undef sBl
    #undef sC
}

// round r: mode 0 = init (r==0), 1 = damped loop (1..n_eps), 2 = final (n_eps+1)
__device__ __forceinline__ bool round_cfg(const float* ws, int r, int& mode, float& eps,
                                          float& inv_eps, int& cur, int& nxt) {
    const int* ei = (const int*)(ws + F_EPS);
    int n_eps = ei[0];
    if (r > n_eps + 1) return false;
    mode = (r == 0) ? 0 : ((r <= n_eps) ? 1 : 2);
    int eidx = (r == 0) ? 0 : ((r - 1 < n_eps - 1) ? r - 1 : n_eps - 1);
    eps = ws[F_EPS + 8 + eidx];
    inv_eps = 1.0f / eps;
    cur = r & 1; nxt = cur ^ 1;
    return true;
}

// ======== SYM PATH: fused per-round kernel, LOAD-BALANCED ========
// blocks [0, Bq*NBAND): op0 (C_xy) full rows -> f_ba + col partials -> F_CP
// blocks [Bq*NBAND, Bq*NBAND + 2*Bq*NBAND/2): sym ops; block j handles bands
//   I=j AND I=NBAND-1-j sequentially -> uniform 16x4112 elements per block.
__global__ __launch_bounds__(256) void k_iter2(float* __restrict__ ws, int r) {
    int mode, cur, nxt; float eps, inv_eps;
    if (!round_cfg(ws, r, mode, eps, inv_eps, cur, nxt)) return;
    float ie2 = inv_eps * LOG2E;
    float epsln2 = eps * LN2;
    float nkq = -DQ_SCALE * ie2;

    int bid = blockIdx.x;
    int w = threadIdx.x >> 6, lane = threadIdx.x & 63;
    __shared__ float rowpart[RBAND][4];

    if (bid < Bq * NBAND) {
        // ---------- op0 (C_xy), R10-proven body ----------
        int b = bid / NBAND;
        int band = bid % NBAND;
        int row0 = band * RBAND;
        int colA = w * 1024 + lane * 8;
        int colB = colA + 512;
        const unsigned short* C = (const unsigned short*)(ws + F_C) + ((size_t)b * Nq + row0) * Nq;
        const float* gdual = ws + F_FG + ((size_t)cur * 4 + 1) * (Bq * Nq) + (size_t)b * Nq; // g_ab
        const float* fdual = ws + F_FG + ((size_t)cur * 4 + 0) * (Bq * Nq) + (size_t)b * Nq; // f_ba

        float pa[16];
        if (mode != 0) {
            float4 g0 = *(const float4*)&gdual[colA];
            float4 g1 = *(const float4*)&gdual[colA + 4];
            float4 g2 = *(const float4*)&gdual[colB];
            float4 g3 = *(const float4*)&gdual[colB + 4];
            float gv[16] = {g0.x, g0.y, g0.z, g0.w, g1.x, g1.y, g1.z, g1.w,
                            g2.x, g2.y, g2.z, g2.w, g3.x, g3.y, g3.z, g3.w};
            #pragma unroll
            for (int j = 0; j < 16; j++) pa[j] = exp2f(fminf(gv[j] * ie2, ACLAMP));
        } else {
            #pragma unroll
            for (int j = 0; j < 16; j++) pa[j] = 1.f;
        }
        float cs[16];
        #pragma unroll
        for (int j = 0; j < 16; j++) cs[j] = 0.f;

        #pragma unroll 2
        for (int i = 0; i < RBAND; i += 2) {
            uint4 cA0 = *(const uint4*)&C[(size_t)i * Nq + colA];
            uint4 cB0 = *(const uint4*)&C[(size_t)i * Nq + colB];
            uint4 cA1 = *(const uint4*)&C[(size_t)(i + 1) * Nq + colA];
            uint4 cB1 = *(const uint4*)&C[(size_t)(i + 1) * Nq + colB];
            float pb0 = 1.f, pb1 = 1.f;
            if (mode != 0) {
                pb0 = exp2f(fminf(fdual[row0 + i] * ie2, ACLAMP));
                pb1 = exp2f(fminf(fdual[row0 + i + 1] * ie2, ACLAMP));
            }
            unsigned u0[8] = {cA0.x, cA0.y, cA0.z, cA0.w, cB0.x, cB0.y, cB0.z, cB0.w};
            unsigned u1[8] = {cA1.x, cA1.y, cA1.z, cA1.w, cB1.x, cB1.y, cB1.z, cB1.w};
            float rs0 = 0.f, rs1 = 0.f;
            #pragma unroll
            for (int j = 0; j < 16; j++) {
                float e0 = exp2f((float)((u0[j >> 1] >> ((j & 1) * 16)) & 0xffffu) * nkq);
                float e1 = exp2f((float)((u1[j >> 1] >> ((j & 1) * 16)) & 0xffffu) * nkq);
                rs0 = fmaf(pa[j], e0, rs0);
                rs1 = fmaf(pa[j], e1, rs1);
                cs[j] = fmaf(pb0, e0, fmaf(pb1, e1, cs[j]));
            }
            #pragma unroll
            for (int o = 32; o > 0; o >>= 1) {
                rs0 += __shfl_xor(rs0, o);
                rs1 += __shfl_xor(rs1, o);
            }
            if (lane == 0) { rowpart[i][w] = rs0; rowpart[i + 1][w] = rs1; }
        }
        __syncthreads();

        if (threadIdx.x < RBAND) {
            int gr = row0 + threadIdx.x;
            const float* rp = rowpart[threadIdx.x];
            float s = (rp[0] + rp[1]) + (rp[2] + rp[3]);
            float ft = -epsln2 * (WL2 + log2f(fmaxf(s, SFLOOR)));
            float* outp = ws + F_FG + ((size_t)nxt * 4 + 0) * (Bq * Nq) + (size_t)b * Nq;
            const float* oldp = ws + F_FG + ((size_t)cur * 4 + 0) * (Bq * Nq) + (size_t)b * Nq;
            outp[gr] = (mode == 1) ? 0.5f * (oldp[gr] + ft) : ft;
        }
        float* cp = ws + F_CP + ((size_t)b * NBAND + band) * Nq;
        *(float4*)&cp[colA]     = make_float4(cs[0], cs[1], cs[2], cs[3]);
        *(float4*)&cp[colA + 4] = make_float4(cs[4], cs[5], cs[6], cs[7]);
        *(float4*)&cp[colB]     = make_float4(cs[8], cs[9], cs[10], cs[11]);
        *(float4*)&cp[colB + 4] = make_float4(cs[12], cs[13], cs[14], cs[15]);
    } else {
        // ---------- sym ops (xx, yy): paired upper-triangle bands ----------
        int sid = bid - Bq * NBAND;          // [0, 2 * Bq * NBAND/2)
        int op = 1 + sid / (Bq * (NBAND / 2));
        int rem = sid % (Bq * (NBAND / 2));
        int b = rem / (NBAND / 2);
        int jj = rem % (NBAND / 2);
        const unsigned short* Cm = (const unsigned short*)(ws + F_C)
                                   + (size_t)op * GSZ + (size_t)b * Nq * Nq;
        int arr = (op == 1) ? 2 : 3;         // f_aa / g_bb
        const float* dual = ws + F_FG + ((size_t)cur * 4 + arr) * (Bq * Nq) + (size_t)b * Nq;

        for (int half = 0; half < 2; half++) {
            int I = half ? (NBAND - 1 - jj) : jj;
            int S = I * RBAND;               // first row and first stored col
            float* cps = ws + F_CPS + (((size_t)(op - 1) * Bq + b) * NBAND + I) * Nq;

            float pb[RBAND];
            #pragma unroll
            for (int i = 0; i < RBAND; i++)
                pb[i] = (mode != 0) ? exp2f(fminf(dual[S + i] * ie2, ACLAMP)) : 1.f;
            float rs[RBAND];
            #pragma unroll
            for (int i = 0; i < RBAND; i++) rs[i] = 0.f;

            for (int t = w; S + t * 512 < Nq; t += 4) {
                int c = S + t * 512 + lane * 8;
                bool valid = (c < Nq);
                float pac[8];
                if (mode != 0 && valid) {
                    float4 g0 = *(const float4*)&dual[c];
                    float4 g1 = *(const float4*)&dual[c + 4];
                    float gv[8] = {g0.x, g0.y, g0.z, g0.w, g1.x, g1.y, g1.z, g1.w};
                    #pragma unroll
                    for (int j = 0; j < 8; j++) pac[j] = exp2f(fminf(gv[j] * ie2, ACLAMP));
                } else {
                    #pragma unroll
                    for (int j = 0; j < 8; j++) pac[j] = 1.f;
                }
                float csl[8];
                #pragma unroll
                for (int j = 0; j < 8; j++) csl[j] = 0.f;
                #pragma unroll 2
                for (int i = 0; i < RBAND; i++) {
                    float e[8];
                    if (valid) {
                        uint4 cu = *(const uint4*)&Cm[(size_t)(S + i) * Nq + c];
                        unsigned uw[4] = {cu.x, cu.y, cu.z, cu.w};
                        #pragma unroll
                        for (int j = 0; j < 8; j++)
                            e[j] = exp2f((float)((uw[j >> 1] >> ((j & 1) * 16)) & 0xffffu) * nkq);
                    } else {
                        #pragma unroll
                        for (int j = 0; j < 8; j++) e[j] = 0.f;
                    }
                    #pragma unroll
                    for (int j = 0; j < 8; j++) rs[i] = fmaf(pac[j], e[j], rs[i]);
                    #pragma unroll
                    for (int j = 0; j < 8; j++) csl[j] = fmaf(pb[i], e[j], csl[j]);
                }
                if (valid && c >= S + RBAND) {   // diag-tile cols counted in rs
                    *(float4*)&cps[c]     = make_float4(csl[0], csl[1], csl[2], csl[3]);
                    *(float4*)&cps[c + 4] = make_float4(csl[4], csl[5], csl[6], csl[7]);
                }
            }
            #pragma unroll
            for (int i = 0; i < RBAND; i++) {
                float v = rs[i];
                #pragma unroll
                for (int o = 32; o > 0; o >>= 1) v += __shfl_xor(v, o);
                if (lane == 0) rowpart[i][w] = v;
            }
            __syncthreads();
            if (threadIdx.x < RBAND) {
                const float* rp = rowpart[threadIdx.x];
                cps[S + threadIdx.x] = (rp[0] + rp[1]) + (rp[2] + rp[3]);  // row partial
            }
            __syncthreads();                 // rowpart reused by next half
        }
    }
}

// ======== SYM PATH combine: g_ab (kind 0), f_aa (1), g_bb (2) ========
__global__ __launch_bounds__(256) void k_comb2(float* __restrict__ ws, int r) {
    int mode, cur, nxt; float eps, inv_eps;
    if (!round_cfg(ws, r, mode, eps, inv_eps, cur, nxt)) return;
    float epsln2 = eps * LN2;
    int q = threadIdx.x >> 6, cidx = threadIdx.x & 63;
    int g = blockIdx.x * 64 + cidx;         // [0, 3*Bq*Nq)
    int kind = g / (Bq * Nq);
    int rem = g % (Bq * Nq);
    int b = rem >> 12, m = rem & (Nq - 1);
    const float* cp;
    int J, arr;
    if (kind == 0) { cp = ws + F_CP + (size_t)b * NBAND * Nq; J = NBAND - 1; arr = 1; }
    else {
        cp = ws + F_CPS + ((size_t)(kind - 1) * Bq + b) * NBAND * Nq;
        J = m >> 4; arr = (kind == 1) ? 2 : 3;
    }
    int k0 = q * (NBAND / 4);
    int k1 = (q + 1) * (NBAND / 4);
    if (k1 > J + 1) k1 = J + 1;
    float S = 0.f;
    for (int k = k0; k < k1; k++) S += cp[(size_t)k * Nq + m];
    __shared__ float part[4][64];
    part[q][cidx] = S;
    __syncthreads();
    if (threadIdx.x < 64) {                 // q==0 threads: same g/kind/b/m/arr
        float St = (part[0][cidx] + part[1][cidx]) + (part[2][cidx] + part[3][cidx]);
        float gt = -epsln2 * (WL2 + log2f(fmaxf(St, SFLOOR)));
        float* outp = ws + F_FG + ((size_t)nxt * 4 + arr) * (Bq * Nq) + (size_t)b * Nq;
        const float* oldp = ws + F_FG + ((size_t)cur * 4 + arr) * (Bq * Nq) + (size_t)b * Nq;
        outp[m] = (mode == 1) ? 0.5f * (oldp[m] + gt) : gt;
    }
}

// ======== OLD PATH (R10-proven): full-matrix k_iter + colcomb ========
__global__ __launch_bounds__(256) void k_iter(float* __restrict__ ws, int r) {
    int mode, cur, nxt; float eps, inv_eps;
    if (!round_cfg(ws, r, mode, eps, inv_eps, cur, nxt)) return;
    float ie2 = inv_eps * LOG2E;
    float epsln2 = eps * LN2;
    float nkq = -DQ_SCALE * ie2;

    int bid = blockIdx.x;
    int op = bid / (Bq * NBAND);
    int rem = bid % (Bq * NBAND);
    int b = rem / NBAND;
    int band = rem % NBAND;
    int row0 = band * RBAND;
    int w = threadIdx.x >> 6, lane = threadIdx.x & 63;
    int colA = w * 1024 + lane * 8;
    int colB = colA + 512;

    const unsigned short* C = (const unsigned short*)(ws + F_C)
                              + (size_t)op * GSZ + ((size_t)b * Nq + row0) * Nq;
    int arr_dual = (op == 0) ? 1 : (op == 1 ? 2 : 3);
    int arr_out  = (op == 0) ? 0 : arr_dual;
    const float* gdual = ws + F_FG + ((size_t)cur * 4 + arr_dual) * (Bq * Nq) + (size_t)b * Nq;
    const float* fdual = ws + F_FG + ((size_t)cur * 4 + 0) * (Bq * Nq) + (size_t)b * Nq;

    float pa[16];
    if (mode != 0) {
        float4 g0 = *(const float4*)&gdual[colA];
        float4 g1 = *(const float4*)&gdual[colA + 4];
        float4 g2 = *(const float4*)&gdual[colB];
        float4 g3 = *(const float4*)&gdual[colB + 4];
        float gv[16] = {g0.x, g0.y, g0.z, g0.w, g1.x, g1.y, g1.z, g1.w,
                        g2.x, g2.y, g2.z, g2.w, g3.x, g3.y, g3.z, g3.w};
        #pragma unroll
        for (int j = 0; j < 16; j++) pa[j] = exp2f(fminf(gv[j] * ie2, ACLAMP));
    } else {
        #pragma unroll
        for (int j = 0; j < 16; j++) pa[j] = 1.f;
    }
    float cs[16];
    #pragma unroll
    for (int j = 0; j < 16; j++) cs[j] = 0.f;

    __shared__ float rowpart[RBAND][4];

    #pragma unroll 2
    for (int i = 0; i < RBAND; i += 2) {
        uint4 cA0 = *(const uint4*)&C[(size_t)i * Nq + colA];
        uint4 cB0 = *(const uint4*)&C[(size_t)i * Nq + colB];
        uint4 cA1 = *(const uint4*)&C[(size_t)(i + 1) * Nq + colA];
        uint4 cB1 = *(const uint4*)&C[(size_t)(i + 1) * Nq + colB];
        float pb0 = 1.f, pb1 = 1.f;
        if (op == 0 && mode != 0) {
            pb0 = exp2f(fminf(fdual[row0 + i] * ie2, ACLAMP));
            pb1 = exp2f(fminf(fdual[row0 + i + 1] * ie2, ACLAMP));
        }
        unsigned u0[8] = {cA0.x, cA0.y, cA0.z, cA0.w, cB0.x, cB0.y, cB0.z, cB0.w};
        unsigned u1[8] = {cA1.x, cA1.y, cA1.z, cA1.w, cB1.x, cB1.y, cB1.z, cB1.w};
        float rs0 = 0.f, rs1 = 0.f;
        #pragma unroll
        for (int j = 0; j < 16; j++) {
            float e0 = exp2f((float)((u0[j >> 1] >> ((j & 1) * 16)) & 0xffffu) * nkq);
            float e1 = exp2f((float)((u1[j >> 1] >> ((j & 1) * 16)) & 0xffffu) * nkq);
            rs0 = fmaf(pa[j], e0, rs0);
            rs1 = fmaf(pa[j], e1, rs1);
            if (op == 0) cs[j] = fmaf(pb0, e0, fmaf(pb1, e1, cs[j]));
        }
        #pragma unroll
        for (int o = 32; o > 0; o >>= 1) {
            rs0 += __shfl_xor(rs0, o);
            rs1 += __shfl_xor(rs1, o);
        }
        if (lane == 0) { rowpart[i][w] = rs0; rowpart[i + 1][w] = rs1; }
    }
    __syncthreads();

    if (threadIdx.x < RBAND) {
        int gr = row0 + threadIdx.x;
        const float* rp = rowpart[threadIdx.x];
        float s = (rp[0] + rp[1]) + (rp[2] + rp[3]);
        float ft = -epsln2 * (WL2 + log2f(fmaxf(s, SFLOOR)));
        float* outp = ws + F_FG + ((size_t)nxt * 4 + arr_out) * (Bq * Nq) + (size_t)b * Nq;
        const float* oldp = ws + F_FG + ((size_t)cur * 4 + arr_out) * (Bq * Nq) + (size_t)b * Nq;
        outp[gr] = (mode == 1) ? 0.5f * (oldp[gr] + ft) : ft;
    }

    if (op == 0) {
        float* cp = ws + F_CP + ((size_t)b * NBAND + band) * Nq;
        *(float4*)&cp[colA]     = make_float4(cs[0], cs[1], cs[2], cs[3]);
        *(float4*)&cp[colA + 4] = make_float4(cs[4], cs[5], cs[6], cs[7]);
        *(float4*)&cp[colB]     = make_float4(cs[8], cs[9], cs[10], cs[11]);
        *(float4*)&cp[colB + 4] = make_float4(cs[12], cs[13], cs[14], cs[15]);
    }
}

__global__ __launch_bounds__(256) void k_colcomb(float* __restrict__ ws, int r) {
    int mode, cur, nxt; float eps, inv_eps;
    if (!round_cfg(ws, r, mode, eps, inv_eps, cur, nxt)) return;
    float epsln2 = eps * LN2;
    int q = threadIdx.x >> 6, c = threadIdx.x & 63;
    int idx = blockIdx.x * 64 + c;
    int b = idx >> 12, m = idx & (Nq - 1);
    const float* cp = ws + F_CP + (size_t)b * NBAND * Nq + m;
    float S = 0.f;
    #pragma unroll 8
    for (int k = q * (NBAND / 4); k < (q + 1) * (NBAND / 4); k++)
        S += cp[(size_t)k * Nq];
    __shared__ float part[4][64];
    part[q][c] = S;
    __syncthreads();
    if (threadIdx.x < 64) {
        float St = (part[0][c] + part[1][c]) + (part[2][c] + part[3][c]);
        float gt = -epsln2 * (WL2 + log2f(fmaxf(St, SFLOOR)));
        float* outp = ws + F_FG + ((size_t)nxt * 4 + 1) * (Bq * Nq) + (size_t)b * Nq;
        const float* oldp = ws + F_FG + ((size_t)cur * 4 + 1) * (Bq * Nq) + (size_t)b * Nq;
        outp[m] = (mode == 1) ? 0.5f * (oldp[m] + gt) : gt;
    }
}

// ---------------- fallback: fused recompute + row softmin (small ws) ----------------
__global__ __launch_bounds__(256) void k_fused(float* __restrict__ ws, int r) {
    int mode, cur, nxt; float eps, inv_eps;
    if (!round_cfg(ws, r, mode, eps, inv_eps, cur, nxt)) return;
    int op = blockIdx.z, b = blockIdx.y;
    int tr = blockIdx.x * 64;
    const float* A  = ws + ((op == 1 || op == 3) ? F_YN : F_XN) + (size_t)b * Nq * Dq;
    const float* Bp = ws + ((op == 0 || op == 3) ? F_YN : F_XN) + (size_t)b * Nq * Dq;
    int dual_arr = (op == 0) ? 1 : (op == 1) ? 0 : (op == 2) ? 2 : 3;
    int out_arr  = (op == 0) ? 0 : (op == 1) ? 1 : (op == 2) ? 2 : 3;
    const float* hdual = ws + F_FG + ((size_t)cur * 4 + dual_arr) * (Bq * Nq) + (size_t)b * Nq;

    __shared__ float As[64][65], Bs[64][65];
    #pragma unroll
    for (int i = 0; i < 16; i++) {
        int idx = threadIdx.x + 256 * i;
        As[idx >> 6][idx & 63] = A[(size_t)(tr + (idx >> 6)) * Dq + (idx & 63)];
    }
    int tx = threadIdx.x & 15, ty = threadIdx.x >> 4;
    float m_i[4], s_i[4];
    #pragma unroll
    for (int i = 0; i < 4; i++) { m_i[i] = -INFINITY; s_i[i] = 0.f; }

    for (int tc = 0; tc < Nq; tc += 64) {
        __syncthreads();
        #pragma unroll
        for (int i = 0; i < 16; i++) {
            int idx = threadIdx.x + 256 * i;
            Bs[idx >> 6][idx & 63] = Bp[(size_t)(tc + (idx >> 6)) * Dq + (idx & 63)];
        }
        __syncthreads();
        float acc[4][4] = {};
        #pragma unroll
        for (int dd = 0; dd < 64; dd++) {
            float a[4], bb[4];
            #pragma unroll
            for (int i = 0; i < 4; i++) a[i] = As[ty * 4 + i][dd];
            #pragma unroll
            for (int j = 0; j < 4; j++) bb[j] = Bs[tx * 4 + j][dd];
            #pragma unroll
            for (int i = 0; i < 4; i++)
                #pragma unroll
                for (int j = 0; j < 4; j++) acc[i][j] = fmaf(a[i], bb[j], acc[i][j]);
        }
        float hv[4];
        #pragma unroll
        for (int j = 0; j < 4; j++)
            hv[j] = (mode == 0) ? 0.f : hdual[tc + tx * 4 + j];
        #pragma unroll
        for (int i = 0; i < 4; i++) {
            float v[4], tm = -INFINITY;
            #pragma unroll
            for (int j = 0; j < 4; j++) {
                float c = 1.0f - acc[i][j];
                v[j] = W_LOG + (hv[j] - c * c) * inv_eps;
                tm = fmaxf(tm, v[j]);
            }
            float nm = fmaxf(m_i[i], tm);
            float add = 0.f;
            #pragma unroll
            for (int j = 0; j < 4; j++) add += expf(v[j] - nm);
            s_i[i] = s_i[i] * expf(m_i[i] - nm) + add;
            m_i[i] = nm;
        }
    }
    #pragma unroll
    for (int o = 1; o < 16; o <<= 1) {
        #pragma unroll
        for (int i = 0; i < 4; i++) {
            float om = __shfl_xor(m_i[i], o);
            float os = __shfl_xor(s_i[i], o);
            float M = fmaxf(m_i[i], om);
            s_i[i] = s_i[i] * expf(m_i[i] - M) + os * expf(om - M);
            m_i[i] = M;
        }
    }
    if (tx == 0) {
        float* outp = ws + F_FG + ((size_t)nxt * 4 + out_arr) * (Bq * Nq) + (size_t)b * Nq;
        const float* oldp = ws + F_FG + ((size_t)cur * 4 + out_arr) * (Bq * Nq) + (size_t)b * Nq;
        #pragma unroll
        for (int i = 0; i < 4; i++) {
            int n = tr + ty * 4 + i;
            float ft = -eps * (m_i[i] + logf(s_i[i]));
            outp[n] = (mode == 1) ? 0.5f * (oldp[n] + ft) : ft;
        }
    }
}

// ---------------- final cost ----------------
__global__ __launch_bounds__(256) void k_final(const float* __restrict__ ws,
                                               float* __restrict__ out) {
    const int* ei = (const int*)(ws + F_EPS);
    int n_eps = ei[0];
    int fin = n_eps & 1;                  // copy written by round n_eps+1
    int b = blockIdx.x;
    const float* fba = ws + F_FG + ((size_t)fin * 4 + 0) * (Bq * Nq) + (size_t)b * Nq;
    const float* gab = ws + F_FG + ((size_t)fin * 4 + 1) * (Bq * Nq) + (size_t)b * Nq;
    const float* faa = ws + F_FG + ((size_t)fin * 4 + 2) * (Bq * Nq) + (size_t)b * Nq;
    const float* gbb = ws + F_FG + ((size_t)fin * 4 + 3) * (Bq * Nq) + (size_t)b * Nq;
    float s = 0.f;
    for (int n = threadIdx.x; n < Nq; n += 256)
        s += (fba[n] - faa[n]) + (gab[n] - gbb[n]);
    #pragma unroll
    for (int o = 32; o > 0; o >>= 1) s += __shfl_xor(s, o);
    __shared__ float red[4];
    if ((threadIdx.x & 63) == 0) red[threadIdx.x >> 6] = s;
    __syncthreads();
    if (threadIdx.x == 0)
        out[b] = (red[0] + red[1] + red[2] + red[3]) * (1.0f / Nq);
}

// sentinel: ws too small even for the fallback
__global__ void k_sentinel(float* out, int n) {
    if ((int)threadIdx.x < n) out[threadIdx.x] = 2.0e9f;
}

extern "C" void kernel_launch(void* const* d_in, const int* in_sizes, int n_in,
                              void* d_out, int out_size, void* d_ws, size_t ws_size,
                              hipStream_t stream) {
    const float* x = (const float*)d_in[0];
    const float* y = (const float*)d_in[1];
    float* out = (float*)d_out;
    float* ws = (float*)d_ws;

    bool sym   = ws_size >= F_TOTAL_SYM * sizeof(float);   // ~234 MB
    bool big   = ws_size >= F_TOTAL_OLD * sizeof(float);   // ~218 MB (R10-proven)
    bool small = ws_size >= F_TOTAL_S * sizeof(float);     // ~17 MB fallback

    if (!small) {
        k_sentinel<<<1, 64, 0, stream>>>(out, out_size);
        return;
    }

    k_normalize<<<(2 * Bq * Nq * 64) / 256, 256, 0, stream>>>(x, y, ws);
    k_minmax<<<64, 256, 0, stream>>>(x, y, ws);
    k_eps<<<1, 64, 0, stream>>>(ws);

    if (sym) {
        k_gram_mfma<<<dim3(4096, Bq, 3), 256, 0, stream>>>(ws, 1);
        int nblk = Bq * NBAND + 2 * Bq * (NBAND / 2);   // 512 op0 + 512 sym-paired
        for (int r = 0; r < MAXR; r++) {
            k_iter2<<<nblk, 256, 0, stream>>>(ws, r);
            k_comb2<<<(3 * Bq * Nq) / 64, 256, 0, stream>>>(ws, r);
        }
    } else if (big) {
        k_gram_mfma<<<dim3(4096, Bq, 3), 256, 0, stream>>>(ws, 0);
        for (int r = 0; r < MAXR; r++) {
            k_iter<<<3 * Bq * NBAND, 256, 0, stream>>>(ws, r);
            k_colcomb<<<(Bq * Nq) / 64, 256, 0, stream>>>(ws, r);
        }
    } else {
        for (int r = 0; r < MAXR; r++) {
            k_fused<<<dim3(Nq / 64, Bq, 4), 256, 0, stream>>>(ws, r);
        }
    }

    k_final<<<Bq, 256, 0, stream>>>(ws, out);
}

// Round 13
// 683.271 us; speedup vs baseline: 1.4307x; 1.4307x over previous
//
#include <hip/hip_runtime.h>
#include <math.h>

// Problem constants
#define Bq 2
#define Nq 4096
#define Dq 64
#define MAXR 14          // rounds launched = supports n_eps up to 12 (diameter <= ~187)
#define RBAND 16         // rows per k_iter block (16 -> 1536 blocks)
#define NBAND (Nq / RBAND)            // 256 row-bands (= col-partial count per col)
#define W_LOG (-8.317766166719343f)   // -log(4096) (N == M, uniform weights)
#define WL2   (-12.0f)                // W_LOG * LOG2E = -log2(4096), EXACT
#define LOG2E 1.4426950408889634f
#define LN2   0.6931471805599453f
#define DQ_SCALE (4.0f / 65535.0f)    // u16 -> C dequant
#define Q_SCALE  16383.75f            // C -> u16 quant (65535/4, exact in f32)
#define ACLAMP 88.0f                  // exp2-arg clamp on hoisted duals (legit max ~72)
#define SFLOOR 1e-30f                 // LSE sum floor: prevents log(0)

// ---- workspace layout (float offsets) ----
#define F_XN   ((size_t)0)                               // normalized x f32: B*N*D
#define F_YN   (F_XN + (size_t)Bq * Nq * Dq)             // normalized y f32
#define F_XH   (F_YN + (size_t)Bq * Nq * Dq)             // bf16 hi(x): B*N*D u16
#define F_XL   (F_XH + (size_t)Bq * Nq * Dq / 2)         // bf16 lo(x)
#define F_YH   (F_XL + (size_t)Bq * Nq * Dq / 2)
#define F_YL   (F_YH + (size_t)Bq * Nq * Dq / 2)
#define F_FG   (F_YL + (size_t)Bq * Nq * Dq / 2)         // duals: 2 copies x 4 arrays x B*N
#define F_EPS  (F_FG + (size_t)2 * 4 * Bq * Nq)          // [0..7]=ints, [8..]=eps values
#define F_MM   (F_EPS + 64)                              // minmax partials: 64 x 128
#define F_CP   (F_MM + (size_t)64 * 128)                 // col partials: B*NBAND*N (sum only)
#define F_C    (((F_CP + (size_t)Bq * NBAND * Nq) + 3) & ~(size_t)3)  // 3 cost mats u16, 16B-aligned
#define GSZ    ((size_t)Bq * Nq * Nq)                    // u16 elements per matrix
#define F_TOTAL_P (F_C + 3 * GSZ / 2)                    // ~218 MB
#define F_TOTAL_S (F_C)                                  // ~17 MB fallback footprint

typedef short short8v __attribute__((ext_vector_type(8)));   // 8 bf16 bits (4 VGPRs)
typedef float f32x4 __attribute__((ext_vector_type(4)));

__device__ __forceinline__ unsigned short f2bf(float f) {
    unsigned u = __float_as_uint(f);
    unsigned r = (u + 0x7fffu + ((u >> 16) & 1u)) >> 16;   // RNE
    return (unsigned short)r;
}
__device__ __forceinline__ float bf2f(unsigned short b) {
    return __uint_as_float(((unsigned)b) << 16);
}

// ---------------- normalize points (+ split-bf16 copies) ----------------
__global__ __launch_bounds__(256) void k_normalize(const float* __restrict__ x,
                                                   const float* __restrict__ y,
                                                   float* __restrict__ ws) {
    int gid = blockIdx.x * 256 + threadIdx.x;
    int wave = gid >> 6;                // point id across both tensors
    int lane = gid & 63;                // dim (D == 64)
    int tensor = wave / (Bq * Nq);
    int p = wave % (Bq * Nq);
    const float* src = tensor ? y : x;
    float v = src[(size_t)p * Dq + lane];
    float s = v * v;
    #pragma unroll
    for (int o = 32; o > 0; o >>= 1) s += __shfl_xor(s, o);
    float vn = v / sqrtf(s);
    float* dst = ws + (tensor ? F_YN : F_XN);
    dst[(size_t)p * Dq + lane] = vn;
    unsigned short hb = f2bf(vn);
    float lo = vn - bf2f(hb);
    unsigned short lb = f2bf(lo);
    unsigned short* dh = (unsigned short*)(ws + (tensor ? F_YH : F_XH));
    unsigned short* dl = (unsigned short*)(ws + (tensor ? F_YL : F_XL));
    dh[(size_t)p * Dq + lane] = hb;
    dl[(size_t)p * Dq + lane] = lb;
}

// ---------------- per-dim max/min partials (raw inputs, both clouds) ----------------
__global__ __launch_bounds__(256) void k_minmax(const float* __restrict__ x,
                                                const float* __restrict__ y,
                                                float* __restrict__ ws) {
    int d = threadIdx.x & 63, q = threadIdx.x >> 6;
    int p0 = blockIdx.x * 256;
    float mx = -INFINITY, mn = INFINITY;
    for (int p = p0 + q; p < p0 + 256; p += 4) {
        const float* src = (p < Bq * Nq) ? x : y;
        int pp = (p < Bq * Nq) ? p : p - Bq * Nq;
        float v = src[(size_t)pp * Dq + d];
        mx = fmaxf(mx, v); mn = fminf(mn, v);
    }
    __shared__ float smx[4][64], smn[4][64];
    smx[q][d] = mx; smn[q][d] = mn;
    __syncthreads();
    if (threadIdx.x < 64) {
        float a = fmaxf(fmaxf(smx[0][d], smx[1][d]), fmaxf(smx[2][d], smx[3][d]));
        float i = fminf(fminf(smn[0][d], smn[1][d]), fminf(smn[2][d], smn[3][d]));
        ws[F_MM + (size_t)blockIdx.x * 128 + d] = a;
        ws[F_MM + (size_t)blockIdx.x * 128 + 64 + d] = i;
    }
}

// ---------------- diameter + eps schedule (np.arange semantics, f64) ----------------
__global__ void k_eps(float* __restrict__ ws) {
    int d = threadIdx.x;  // 64 threads = 1 wave
    float mx = -INFINITY, mn = INFINITY;
    for (int k = 0; k < 64; k++) {
        mx = fmaxf(mx, ws[F_MM + (size_t)k * 128 + d]);
        mn = fminf(mn, ws[F_MM + (size_t)k * 128 + 64 + d]);
    }
    float r = mx - mn;
    float r2 = r * r;
    #pragma unroll
    for (int o = 32; o > 0; o >>= 1) r2 += __shfl_xor(r2, o);
    if (d == 0) {
        double dd = (double)sqrtf(r2);               // f32-rounded diameter like np
        double start = 2.0 * log(dd);                // P * log(diameter)
        double stop  = 2.0 * log(sqrt(0.1));         // P * log(BLUR)
        double step  = 2.0 * log(0.5);               // P * log(SCALING)
        double lend = ceil((stop - start) / step);
        int len = (lend <= 0.0) ? 0 : (int)lend;
        int n = len + 2;                             // len(eps_list)
        if (n > MAXR - 2) n = MAXR - 2;
        int* ei = (int*)(ws + F_EPS);
        ei[0] = n;
        float* ev = ws + F_EPS + 8;
        ev[0] = (float)(dd * dd);
        for (int i = 0; i < len && i + 1 < n - 1; i++)
            ev[1 + i] = (float)exp(start + i * step);
        ev[n - 1] = 0.1f;                            // BLUR**P
    }
}

// ------- cost matrices via split-bf16 MFMA, LDS-staged 64x64 tiles -> u16 -------
// op0 C_xy, op1 C_xx, op2 C_yy.  sC aliases sAh (dead after frag-reg loads).
// sC column-blocks XOR-swizzled by (row>>1)&7 to spread kb-groups across banks.
__global__ __launch_bounds__(256) void k_gram_mfma(float* __restrict__ ws) {
    int op = blockIdx.z, b = blockIdx.y;
    int tr = (blockIdx.x & 63) * 64;
    int tc = (blockIdx.x >> 6) * 64;
    const unsigned short* AH = (const unsigned short*)(ws + (op == 2 ? F_YH : F_XH)) + (size_t)b * Nq * Dq;
    const unsigned short* AL = (const unsigned short*)(ws + (op == 2 ? F_YL : F_XL)) + (size_t)b * Nq * Dq;
    const unsigned short* BH = (const unsigned short*)(ws + (op == 1 ? F_XH : F_YH)) + (size_t)b * Nq * Dq;
    const unsigned short* BL = (const unsigned short*)(ws + (op == 1 ? F_XL : F_YL)) + (size_t)b * Nq * Dq;

    // pitch 72 u16 (144 B): 16B-aligned rows; sbuf[0] doubles as sC after barrier
    __shared__ unsigned short sbuf[4][64][72];
    #define sAh (sbuf[0])
    #define sAl (sbuf[1])
    #define sBh (sbuf[2])
    #define sBl (sbuf[3])
    #define sC  (sbuf[0])

    #pragma unroll
    for (int i = 0; i < 2; i++) {
        int c = threadIdx.x + 256 * i;         // 512 chunks of 8 u16 per matrix
        int row = c >> 3, pos = c & 7;
        size_t sa = (size_t)(tr + row) * Dq + pos * 8;
        size_t sb = (size_t)(tc + row) * Dq + pos * 8;
        *(uint4*)&sAh[row][pos * 8] = *(const uint4*)&AH[sa];
        *(uint4*)&sAl[row][pos * 8] = *(const uint4*)&AL[sa];
        *(uint4*)&sBh[row][pos * 8] = *(const uint4*)&BH[sb];
        *(uint4*)&sBl[row][pos * 8] = *(const uint4*)&BL[sb];
    }
    __syncthreads();

    int w = threadIdx.x >> 6, lane = threadIdx.x & 63;
    int m = lane & 15, kb = lane >> 4;
    int ar = w * 16 + m;
    short8v aH0 = *(const short8v*)&sAh[ar][kb * 8];
    short8v aH1 = *(const short8v*)&sAh[ar][32 + kb * 8];
    short8v aL0 = *(const short8v*)&sAl[ar][kb * 8];
    short8v aL1 = *(const short8v*)&sAl[ar][32 + kb * 8];
    __syncthreads();   // sAh is now dead -> safe to reuse as sC

    #pragma unroll
    for (int cb = 0; cb < 4; cb++) {
        int bc = cb * 16 + m;
        short8v bH0 = *(const short8v*)&sBh[bc][kb * 8];
        short8v bH1 = *(const short8v*)&sBh[bc][32 + kb * 8];
        short8v bL0 = *(const short8v*)&sBl[bc][kb * 8];
        short8v bL1 = *(const short8v*)&sBl[bc][32 + kb * 8];
        f32x4 acc = {0.f, 0.f, 0.f, 0.f};
        acc = __builtin_amdgcn_mfma_f32_16x16x32_bf16(aH0, bH0, acc, 0, 0, 0);
        acc = __builtin_amdgcn_mfma_f32_16x16x32_bf16(aH1, bH1, acc, 0, 0, 0);
        acc = __builtin_amdgcn_mfma_f32_16x16x32_bf16(aL0, bH0, acc, 0, 0, 0);
        acc = __builtin_amdgcn_mfma_f32_16x16x32_bf16(aL1, bH1, acc, 0, 0, 0);
        acc = __builtin_amdgcn_mfma_f32_16x16x32_bf16(aH0, bL0, acc, 0, 0, 0);
        acc = __builtin_amdgcn_mfma_f32_16x16x32_bf16(aH1, bL1, acc, 0, 0, 0);
        // C/D: col = lane&15 (m), row = kb*4 + rr  [m89-verified]
        int colblk = cb * 2 + (m >> 3);        // logical 8-u16 column block
        int within = m & 7;
        #pragma unroll
        for (int rr = 0; rr < 4; rr++) {
            int rowl = w * 16 + kb * 4 + rr;
            float c1 = 1.0f - acc[rr];
            unsigned u = __float2uint_rn(fminf(c1 * c1, 4.0f) * Q_SCALE);
            if (u > 65535u) u = 65535u;
            int swz = colblk ^ ((rowl >> 1) & 7);
            sC[rowl][swz * 8 + within] = (unsigned short)u;
        }
    }
    __syncthreads();

    unsigned short* C = (unsigned short*)(ws + F_C) + (size_t)op * GSZ + (size_t)b * Nq * Nq;
    #pragma unroll
    for (int i = 0; i < 2; i++) {
        int c = threadIdx.x + 256 * i;
        int row = c >> 3, pos = c & 7;
        int swz = pos ^ ((row >> 1) & 7);
        uint4 v = *(const uint4*)&sC[row][swz * 8];
        *(uint4*)&C[(size_t)(tr + row) * Nq + tc + pos * 8] = v;
    }
    #undef sAh
    #undef sAl
    #undef sBh
    #undef sBl
    #undef sC
}

// round r: mode 0 = init (r==0), 1 = damped loop (1..n_eps), 2 = final (n_eps+1)
__device__ __forceinline__ bool round_cfg(const float* ws, int r, int& mode, float& eps,
                                          float& inv_eps, int& cur, int& nxt) {
    const int* ei = (const int*)(ws + F_EPS);
    int n_eps = ei[0];
    if (r > n_eps + 1) return false;
    mode = (r == 0) ? 0 : ((r <= n_eps) ? 1 : 2);
    int eidx = (r == 0) ? 0 : ((r - 1 < n_eps - 1) ? r - 1 : n_eps - 1);
    eps = ws[F_EPS + 8 + eidx];
    inv_eps = 1.0f / eps;
    cur = r & 1; nxt = cur ^ 1;
    return true;
}

// -------- per-round fused kernel: row softmins (3 ops) + col partials (op0) --------
// block = (op, b, 16-row band), 256 threads = 4 waves; wave w owns cols
// [w*1024, w*1024+512) and [w*1024+512, w*1024+1024).
// exp2-factored: pa[j]=exp2(g_j/eps) hoisted; per element only exp2(-C/eps) + FMA.
// (R8-proven inner loop: unroll 2, compiler-scheduled loads — manual prefetch
//  pushed VGPR to 148 and halved occupancy (R9); branch-fused sym bodies
//  regressed via register coupling + per-element inefficiency (R11/R12).)
__global__ __launch_bounds__(256) void k_iter(float* __restrict__ ws, int r) {
    int mode, cur, nxt; float eps, inv_eps;
    if (!round_cfg(ws, r, mode, eps, inv_eps, cur, nxt)) return;
    float ie2 = inv_eps * LOG2E;
    float epsln2 = eps * LN2;
    float nkq = -DQ_SCALE * ie2;        // t = u * nkq ; e = exp2(t) = exp2(-C/eps)

    int bid = blockIdx.x;
    int op = bid / (Bq * NBAND);
    int rem = bid % (Bq * NBAND);
    int b = rem / NBAND;
    int band = rem % NBAND;
    int row0 = band * RBAND;
    int w = threadIdx.x >> 6, lane = threadIdx.x & 63;
    int colA = w * 1024 + lane * 8;     // first 8-col slice
    int colB = colA + 512;              // second 8-col slice

    const unsigned short* C = (const unsigned short*)(ws + F_C)
                              + (size_t)op * GSZ + ((size_t)b * Nq + row0) * Nq;
    int arr_dual = (op == 0) ? 1 : (op == 1 ? 2 : 3);   // g_ab / f_aa / g_bb (row-direction dual)
    int arr_out  = (op == 0) ? 0 : arr_dual;            // f_ba / f_aa / g_bb
    const float* gdual = ws + F_FG + ((size_t)cur * 4 + arr_dual) * (Bq * Nq) + (size_t)b * Nq;
    const float* fdual = ws + F_FG + ((size_t)cur * 4 + 0) * (Bq * Nq) + (size_t)b * Nq; // f_ba

    // hoisted per-column factors pa[j] = exp2(dual_col * ie2)
    float pa[16];
    if (mode != 0) {
        float4 g0 = *(const float4*)&gdual[colA];
        float4 g1 = *(const float4*)&gdual[colA + 4];
        float4 g2 = *(const float4*)&gdual[colB];
        float4 g3 = *(const float4*)&gdual[colB + 4];
        float gv[16] = {g0.x, g0.y, g0.z, g0.w, g1.x, g1.y, g1.z, g1.w,
                        g2.x, g2.y, g2.z, g2.w, g3.x, g3.y, g3.z, g3.w};
        #pragma unroll
        for (int j = 0; j < 16; j++) pa[j] = exp2f(fminf(gv[j] * ie2, ACLAMP));
    } else {
        #pragma unroll
        for (int j = 0; j < 16; j++) pa[j] = 1.f;
    }
    float cs[16];
    #pragma unroll
    for (int j = 0; j < 16; j++) cs[j] = 0.f;

    __shared__ float rowpart[RBAND][4];

    #pragma unroll 2
    for (int i = 0; i < RBAND; i += 2) {
        // row pair: 4 independent loads in flight
        uint4 cA0 = *(const uint4*)&C[(size_t)i * Nq + colA];
        uint4 cB0 = *(const uint4*)&C[(size_t)i * Nq + colB];
        uint4 cA1 = *(const uint4*)&C[(size_t)(i + 1) * Nq + colA];
        uint4 cB1 = *(const uint4*)&C[(size_t)(i + 1) * Nq + colB];
        float pb0 = 1.f, pb1 = 1.f;
        if (op == 0 && mode != 0) {
            pb0 = exp2f(fminf(fdual[row0 + i] * ie2, ACLAMP));       // wave-uniform
            pb1 = exp2f(fminf(fdual[row0 + i + 1] * ie2, ACLAMP));
        }
        unsigned u0[8] = {cA0.x, cA0.y, cA0.z, cA0.w, cB0.x, cB0.y, cB0.z, cB0.w};
        unsigned u1[8] = {cA1.x, cA1.y, cA1.z, cA1.w, cB1.x, cB1.y, cB1.z, cB1.w};
        float rs0 = 0.f, rs1 = 0.f;
        #pragma unroll
        for (int j = 0; j < 16; j++) {
            float e0 = exp2f((float)((u0[j >> 1] >> ((j & 1) * 16)) & 0xffffu) * nkq);
            float e1 = exp2f((float)((u1[j >> 1] >> ((j & 1) * 16)) & 0xffffu) * nkq);
            rs0 = fmaf(pa[j], e0, rs0);
            rs1 = fmaf(pa[j], e1, rs1);
            if (op == 0) cs[j] = fmaf(pb0, e0, fmaf(pb1, e1, cs[j]));
        }
        #pragma unroll
        for (int o = 32; o > 0; o >>= 1) {
            rs0 += __shfl_xor(rs0, o);
            rs1 += __shfl_xor(rs1, o);
        }
        if (lane == 0) { rowpart[i][w] = rs0; rowpart[i + 1][w] = rs1; }
    }
    __syncthreads();

    if (threadIdx.x < RBAND) {
        int gr = row0 + threadIdx.x;
        const float* rp = rowpart[threadIdx.x];
        float s = (rp[0] + rp[1]) + (rp[2] + rp[3]);
        float ft = -epsln2 * (WL2 + log2f(fmaxf(s, SFLOOR)));
        float* outp = ws + F_FG + ((size_t)nxt * 4 + arr_out) * (Bq * Nq) + (size_t)b * Nq;
        const float* oldp = ws + F_FG + ((size_t)cur * 4 + arr_out) * (Bq * Nq) + (size_t)b * Nq;
        outp[gr] = (mode == 1) ? 0.5f * (oldp[gr] + ft) : ft;
    }

    if (op == 0) {
        float* cp = ws + F_CP + ((size_t)b * NBAND + band) * Nq;
        *(float4*)&cp[colA]     = make_float4(cs[0], cs[1], cs[2], cs[3]);
        *(float4*)&cp[colA + 4] = make_float4(cs[4], cs[5], cs[6], cs[7]);
        *(float4*)&cp[colB]     = make_float4(cs[8], cs[9], cs[10], cs[11]);
        *(float4*)&cp[colB + 4] = make_float4(cs[12], cs[13], cs[14], cs[15]);
    }
}

// combine col partials -> g_ab.  128 blocks; wave w sums band-quarter w for 64
// consecutive outputs (fully coalesced 256B reads), LDS combine.
__global__ __launch_bounds__(256) void k_colcomb(float* __restrict__ ws, int r) {
    int mode, cur, nxt; float eps, inv_eps;
    if (!round_cfg(ws, r, mode, eps, inv_eps, cur, nxt)) return;
    float epsln2 = eps * LN2;
    int q = threadIdx.x >> 6, c = threadIdx.x & 63;
    int idx = blockIdx.x * 64 + c;      // output index in [0, Bq*Nq)
    int b = idx >> 12, m = idx & (Nq - 1);
    const float* cp = ws + F_CP + (size_t)b * NBAND * Nq + m;
    float S = 0.f;
    #pragma unroll 8
    for (int k = q * (NBAND / 4); k < (q + 1) * (NBAND / 4); k++)
        S += cp[(size_t)k * Nq];
    __shared__ float part[4][64];
    part[q][c] = S;
    __syncthreads();
    if (threadIdx.x < 64) {
        float St = (part[0][c] + part[1][c]) + (part[2][c] + part[3][c]);
        float gt = -epsln2 * (WL2 + log2f(fmaxf(St, SFLOOR)));
        float* outp = ws + F_FG + ((size_t)nxt * 4 + 1) * (Bq * Nq) + (size_t)b * Nq;
        const float* oldp = ws + F_FG + ((size_t)cur * 4 + 1) * (Bq * Nq) + (size_t)b * Nq;
        outp[m] = (mode == 1) ? 0.5f * (oldp[m] + gt) : gt;
    }
}

// ---------------- fallback: fused recompute + row softmin (small ws) ----------------
__global__ __launch_bounds__(256) void k_fused(float* __restrict__ ws, int r) {
    int mode, cur, nxt; float eps, inv_eps;
    if (!round_cfg(ws, r, mode, eps, inv_eps, cur, nxt)) return;
    int op = blockIdx.z, b = blockIdx.y;
    int tr = blockIdx.x * 64;
    const float* A  = ws + ((op == 1 || op == 3) ? F_YN : F_XN) + (size_t)b * Nq * Dq;
    const float* Bp = ws + ((op == 0 || op == 3) ? F_YN : F_XN) + (size_t)b * Nq * Dq;
    int dual_arr = (op == 0) ? 1 : (op == 1) ? 0 : (op == 2) ? 2 : 3;
    int out_arr  = (op == 0) ? 0 : (op == 1) ? 1 : (op == 2) ? 2 : 3;
    const float* hdual = ws + F_FG + ((size_t)cur * 4 + dual_arr) * (Bq * Nq) + (size_t)b * Nq;

    __shared__ float As[64][65], Bs[64][65];
    #pragma unroll
    for (int i = 0; i < 16; i++) {
        int idx = threadIdx.x + 256 * i;
        As[idx >> 6][idx & 63] = A[(size_t)(tr + (idx >> 6)) * Dq + (idx & 63)];
    }
    int tx = threadIdx.x & 15, ty = threadIdx.x >> 4;
    float m_i[4], s_i[4];
    #pragma unroll
    for (int i = 0; i < 4; i++) { m_i[i] = -INFINITY; s_i[i] = 0.f; }

    for (int tc = 0; tc < Nq; tc += 64) {
        __syncthreads();
        #pragma unroll
        for (int i = 0; i < 16; i++) {
            int idx = threadIdx.x + 256 * i;
            Bs[idx >> 6][idx & 63] = Bp[(size_t)(tc + (idx >> 6)) * Dq + (idx & 63)];
        }
        __syncthreads();
        float acc[4][4] = {};
        #pragma unroll
        for (int dd = 0; dd < 64; dd++) {
            float a[4], bb[4];
            #pragma unroll
            for (int i = 0; i < 4; i++) a[i] = As[ty * 4 + i][dd];
            #pragma unroll
            for (int j = 0; j < 4; j++) bb[j] = Bs[tx * 4 + j][dd];
            #pragma unroll
            for (int i = 0; i < 4; i++)
                #pragma unroll
                for (int j = 0; j < 4; j++) acc[i][j] = fmaf(a[i], bb[j], acc[i][j]);
        }
        float hv[4];
        #pragma unroll
        for (int j = 0; j < 4; j++)
            hv[j] = (mode == 0) ? 0.f : hdual[tc + tx * 4 + j];
        #pragma unroll
        for (int i = 0; i < 4; i++) {
            float v[4], tm = -INFINITY;
            #pragma unroll
            for (int j = 0; j < 4; j++) {
                float c = 1.0f - acc[i][j];
                v[j] = W_LOG + (hv[j] - c * c) * inv_eps;
                tm = fmaxf(tm, v[j]);
            }
            float nm = fmaxf(m_i[i], tm);
            float add = 0.f;
            #pragma unroll
            for (int j = 0; j < 4; j++) add += expf(v[j] - nm);
            s_i[i] = s_i[i] * expf(m_i[i] - nm) + add;
            m_i[i] = nm;
        }
    }
    #pragma unroll
    for (int o = 1; o < 16; o <<= 1) {
        #pragma unroll
        for (int i = 0; i < 4; i++) {
            float om = __shfl_xor(m_i[i], o);
            float os = __shfl_xor(s_i[i], o);
            float M = fmaxf(m_i[i], om);
            s_i[i] = s_i[i] * expf(m_i[i] - M) + os * expf(om - M);
            m_i[i] = M;
        }
    }
    if (tx == 0) {
        float* outp = ws + F_FG + ((size_t)nxt * 4 + out_arr) * (Bq * Nq) + (size_t)b * Nq;
        const float* oldp = ws + F_FG + ((size_t)cur * 4 + out_arr) * (Bq * Nq) + (size_t)b * Nq;
        #pragma unroll
        for (int i = 0; i < 4; i++) {
            int n = tr + ty * 4 + i;
            float ft = -eps * (m_i[i] + logf(s_i[i]));
            outp[n] = (mode == 1) ? 0.5f * (oldp[n] + ft) : ft;
        }
    }
}

// ---------------- final cost ----------------
__global__ __launch_bounds__(256) void k_final(const float* __restrict__ ws,
                                               float* __restrict__ out) {
    const int* ei = (const int*)(ws + F_EPS);
    int n_eps = ei[0];
    int fin = n_eps & 1;                  // copy written by round n_eps+1
    int b = blockIdx.x;
    const float* fba = ws + F_FG + ((size_t)fin * 4 + 0) * (Bq * Nq) + (size_t)b * Nq;
    const float* gab = ws + F_FG + ((size_t)fin * 4 + 1) * (Bq * Nq) + (size_t)b * Nq;
    const float* faa = ws + F_FG + ((size_t)fin * 4 + 2) * (Bq * Nq) + (size_t)b * Nq;
    const float* gbb = ws + F_FG + ((size_t)fin * 4 + 3) * (Bq * Nq) + (size_t)b * Nq;
    float s = 0.f;
    for (int n = threadIdx.x; n < Nq; n += 256)
        s += (fba[n] - faa[n]) + (gab[n] - gbb[n]);
    #pragma unroll
    for (int o = 32; o > 0; o >>= 1) s += __shfl_xor(s, o);
    __shared__ float red[4];
    if ((threadIdx.x & 63) == 0) red[threadIdx.x >> 6] = s;
    __syncthreads();
    if (threadIdx.x == 0)
        out[b] = (red[0] + red[1] + red[2] + red[3]) * (1.0f / Nq);
}

// sentinel: ws too small even for the fallback
__global__ void k_sentinel(float* out, int n) {
    if ((int)threadIdx.x < n) out[threadIdx.x] = 2.0e9f;
}

extern "C" void kernel_launch(void* const* d_in, const int* in_sizes, int n_in,
                              void* d_out, int out_size, void* d_ws, size_t ws_size,
                              hipStream_t stream) {
    const float* x = (const float*)d_in[0];
    const float* y = (const float*)d_in[1];
    float* out = (float*)d_out;
    float* ws = (float*)d_ws;

    bool big   = ws_size >= F_TOTAL_P * sizeof(float);   // ~218 MB
    bool small = ws_size >= F_TOTAL_S * sizeof(float);   // ~17 MB fallback footprint

    if (!small) {
        k_sentinel<<<1, 64, 0, stream>>>(out, out_size);
        return;
    }

    k_normalize<<<(2 * Bq * Nq * 64) / 256, 256, 0, stream>>>(x, y, ws);
    k_minmax<<<64, 256, 0, stream>>>(x, y, ws);
    k_eps<<<1, 64, 0, stream>>>(ws);

    if (big) {
        k_gram_mfma<<<dim3(4096, Bq, 3), 256, 0, stream>>>(ws);
        for (int r = 0; r < MAXR; r++) {
            k_iter<<<3 * Bq * NBAND, 256, 0, stream>>>(ws, r);
            k_colcomb<<<(Bq * Nq) / 64, 256, 0, stream>>>(ws, r);
        }
    } else {
        for (int r = 0; r < MAXR; r++) {
            k_fused<<<dim3(Nq / 64, Bq, 4), 256, 0, stream>>>(ws, r);
        }
    }

    k_final<<<Bq, 256, 0, stream>>>(ws, out);
}